// Round 5
// baseline (232.450 us; speedup 1.0000x reference)
//
#include <hip/hip_runtime.h>

// InfoCNECauchy: loss = mean_r log(sum_{j!=r} sim[r,j]) - mean_r log(sim[r, r^4096])
// sim = t^2/(d2+t^2), d2 = ||f_r||^2 + ||f_c||^2 - 2<f_r,f_c>, t=0.07
//
// R10: NO-LDS gemm. Four falsified theories (bytes x2, L3->L2 locality,
// barrier count /2, wave pool x2) all left gemm at ~70us -> the shared cost
// is the staging machinery itself (m177: staging=90% of GEMM; lesson #7:
// don't LDS-stage what L2-fits; panels are 128KB/tile, L2-resident per R7).
// Key fact (verified by unwinding the XOR swizzle): the LDS path delivers to
// lane l fragment mr exactly the 16 contiguous bytes at
//   fbf[(brow+wrow+mr*16+(l&15))*512 + kt*32 + (l>>4)*8]
// i.e. MFMA fragments are naturally coalesced DIRECT global loads (16 full
// 64B lines per instr; B identical by G=F*F^T symmetry). So: each wave owns
// a 64x64 quadrant, loads fragments straight from L2, zero __shared__, zero
// barriers, zero waitcnts; compiler pipelines loads across an unrolled
// kt-loop with counted vmcnt. 64 acc + 32 frag + addr ~115 regs ->
// __launch_bounds__(256,4): 4 waves/SIMD, 4 blocks/CU. Banded XCD map and
// epilogue kept verbatim (proven).

#define N2 8192
#define DIM 512
#define NT 64 /* 8192/128 tiles per dim */
#define NTILES (NT * (NT + 1) / 2)
#define T2 0.0049f

typedef float floatx4 __attribute__((ext_vector_type(4)));
typedef __bf16 bf16x8 __attribute__((ext_vector_type(8)));
typedef __bf16 bf16x4 __attribute__((ext_vector_type(4)));

// ---- prep: fp32 -> bf16 + row norms + zero rowsum ------------------------
__global__ __launch_bounds__(256) void prep_kernel(const float* __restrict__ f,
                                                   __bf16* __restrict__ fbf,
                                                   float* __restrict__ sq,
                                                   float* __restrict__ rowsum) {
  const int t = threadIdx.x;
  if (t < 2) rowsum[blockIdx.x * 2 + t] = 0.f;
  const int row = blockIdx.x * 2 + (t >> 7);
  const int ci = (t & 127) * 4;
  const float4 v = *(const float4*)(f + (size_t)row * DIM + ci);
  bf16x4 b;
  b[0] = (__bf16)v.x; b[1] = (__bf16)v.y; b[2] = (__bf16)v.z; b[3] = (__bf16)v.w;
  *(bf16x4*)(fbf + (size_t)row * DIM + ci) = b;
  float s = v.x * v.x + v.y * v.y + v.z * v.z + v.w * v.w;
#pragma unroll
  for (int off = 1; off < 64; off <<= 1) s += __shfl_xor(s, off, 64);
  __shared__ float red[4];
  if ((t & 63) == 0) red[t >> 6] = s;
  __syncthreads();
  if ((t & 127) == 0) sq[row] = red[t >> 6] + red[(t >> 6) + 1];
}

// ---- fused GEMM (upper tri, banded XCD order, DIRECT loads) + epilogue ---
__global__ __launch_bounds__(256, 4) void gemm_kernel(const __bf16* __restrict__ fbf,
                                                      const float* __restrict__ sq,
                                                      float* __restrict__ rowsum,
                                                      float* __restrict__ spart) {
  // R5's banded tile decode (empirically best): XCD x owns row-bands
  // by in [4x,4x+4) and [60-4x,64-4x), bx-major, 260 tiles each.
  int by, bx;
  {
    const int x = blockIdx.x & 7;
    int kk = blockIdx.x >> 3;
    int band = x;
    const int n1 = 250 - 16 * x;
    if (kk >= n1) { kk -= n1; band = 15 - x; }
    const int by0 = band * 4;
    int bxx = by0;
    int cnt;
    while (kk >= (cnt = min(4, bxx - by0 + 1))) { kk -= cnt; ++bxx; }
    by = by0 + kk;
    bx = bxx;
  }
  const int brow = by * 128;
  const int bcol = bx * 128;
  const bool diag = (by == bx);

  const int t = threadIdx.x;
  const int lane = t & 63;
  const int w = t >> 6;
  const int wrow = (w >> 1) * 64;
  const int wcol = (w & 1) * 64;
  const int q4 = lane >> 4;  // 0..3
  const int lc = lane & 15;  // 0..15

  floatx4 acc[4][4] = {};

  // Direct per-lane fragment pointers (the exact data the proven LDS path
  // delivered): lane holds A[row = wrow+mr*16+(l&15)][k = kt*32+(l>>4)*8 ..+8]
  const __bf16* pa = fbf + (size_t)(brow + wrow + lc) * DIM + q4 * 8;
  const __bf16* pb = fbf + (size_t)(bcol + wcol + lc) * DIM + q4 * 8;

#pragma unroll 4
  for (int kt = 0; kt < DIM / 32; ++kt) {
    const int k0 = kt * 32;
    bf16x8 af[4], bfr[4];
#pragma unroll
    for (int m = 0; m < 4; ++m) {
      af[m] = *(const bf16x8*)(pa + (size_t)m * 16 * DIM + k0);
      bfr[m] = *(const bf16x8*)(pb + (size_t)m * 16 * DIM + k0);
    }
#pragma unroll
    for (int mr = 0; mr < 4; ++mr)
#pragma unroll
      for (int mc = 0; mc < 4; ++mc)
        acc[mr][mc] =
            __builtin_amdgcn_mfma_f32_16x16x32_bf16(af[mr], bfr[mc], acc[mr][mc], 0, 0, 0);
  }

  // Epilogue. C/D layout: col = lane&15, row = (lane>>4)*4 + reg.
  float sqc[4];
#pragma unroll
  for (int mc = 0; mc < 4; ++mc) sqc[mc] = sq[bcol + wcol + mc * 16 + lc];

  float cs[4] = {0.f, 0.f, 0.f, 0.f};  // column partial sums (off-diag tiles)

#pragma unroll
  for (int mr = 0; mr < 4; ++mr) {
#pragma unroll
    for (int reg = 0; reg < 4; ++reg) {
      const int r = brow + wrow + mr * 16 + q4 * 4 + reg;
      const float sr = sq[r];
      const int pc = r ^ (N2 / 2);
      float rs = 0.f;
#pragma unroll
      for (int mc = 0; mc < 4; ++mc) {
        const int c = bcol + wcol + mc * 16 + lc;
        const float g = acc[mr][mc][reg];
        const float d2 = fmaxf(sr + sqc[mc] - 2.f * g, 0.f);
        const float s = T2 * __builtin_amdgcn_rcpf(d2 + T2);
        if (c != r) rs += s;  // diagonal excluded exactly (diag tiles only)
        cs[mc] += s;          // unused on diag tiles
        if (c == pc) { spart[r] = s; spart[pc] = s; }  // off-diag only, 1 lane
      }
#pragma unroll
      for (int off = 1; off < 16; off <<= 1) rs += __shfl_xor(rs, off, 64);
      if (lc == 0) atomicAdd(&rowsum[r], rs);
    }
  }

  if (!diag) {
#pragma unroll
    for (int mc = 0; mc < 4; ++mc) {
      float v = cs[mc];
      v += __shfl_xor(v, 16, 64);
      v += __shfl_xor(v, 32, 64);
      if (lane < 16) atomicAdd(&rowsum[bcol + wcol + mc * 16 + lane], v);
    }
  }
}

// ---- final scalar reduction ---------------------------------------------
__global__ __launch_bounds__(256) void final_kernel(const float* __restrict__ rowsum,
                                                    const float* __restrict__ spart,
                                                    float* __restrict__ out) {
  const int t = threadIdx.x;
  float a = 0.f;
  for (int r = t; r < N2; r += 256) a += logf(rowsum[r]) - logf(spart[r]);
#pragma unroll
  for (int off = 1; off < 64; off <<= 1) a += __shfl_xor(a, off, 64);
  __shared__ float red[4];
  if ((t & 63) == 0) red[t >> 6] = a;
  __syncthreads();
  if (t == 0) out[0] = (red[0] + red[1] + red[2] + red[3]) * (1.0f / (float)N2);
}

extern "C" void kernel_launch(void* const* d_in, const int* in_sizes, int n_in,
                              void* d_out, int out_size, void* d_ws, size_t ws_size,
                              hipStream_t stream) {
  const float* features = (const float*)d_in[0];
  float* out = (float*)d_out;

  char* ws = (char*)d_ws;
  __bf16* fbf = (__bf16*)ws;                                     // 8 MB
  float* sq = (float*)(ws + (size_t)N2 * DIM * sizeof(__bf16));  // 32 KB
  float* rowsum = sq + N2;                                       // 32 KB
  float* spart = rowsum + N2;                                    // 32 KB

  prep_kernel<<<N2 / 2, 256, 0, stream>>>(features, fbf, sq, rowsum);
  gemm_kernel<<<NTILES, 256, 0, stream>>>(fbf, sq, rowsum, spart);
  final_kernel<<<1, 256, 0, stream>>>(rowsum, spart, out);
}

// Round 7
// 172.601 us; speedup vs baseline: 1.3467x; 1.3467x over previous
//
#include <hip/hip_runtime.h>

// InfoCNECauchy: loss = mean_r log(sum_{j!=r} sim[r,j]) - mean_r log(sim[r, r^4096])
// sim = t^2/(d2+t^2), d2 = ||f_r||^2 + ||f_c||^2 - 2<f_r,f_c>, t=0.07
//
// R11 (resubmit; R6 bench was a GPUAcquisitionTimeout, experiment never ran):
// R8's K-loop verbatim (BK=64, banded XCD map, XOR-swizzled LDS, 0 conflicts,
// 70.6us best). ONE change: NO GLOBAL ATOMICS. R10 post-mortem re-ran the
// cycle model: every pipe <=30% busy at 70us; five structural theories
// falsified (bytes x2, L3->L2 locality, barrier count /2, wave pool x2,
// LDS-vs-direct). Remaining candidate: the 128 lane-atomics/wave to rowsum --
// device-scope RMWs on a non-coherent-L2 chip execute at the L3/fabric
// coherence point (~700+cy, same-line serialization across 8 XCDs), drained
// at wave end while holding the occupancy slot. R11 replaces them with: LDS
// cross-wave combine (reuse aT after last barrier) + plain stores of per-tile
// row/col partials (tri-indexed, 2x 2080x128 f32, +2.1MB ws), then a tiny
// reduce_kernel sums partials into rowsum. spart already atomic-free.
// Clean A/B: gemm ~40-55us => fabric atomics were the floor; unchanged =>
// exonerated, only the schedule interior remains.

#define N2 8192
#define DIM 512
#define NT 64 /* 8192/128 tiles per dim */
#define NTILES (NT * (NT + 1) / 2)
#define T2 0.0049f

typedef float floatx4 __attribute__((ext_vector_type(4)));
typedef __bf16 bf16x8 __attribute__((ext_vector_type(8)));
typedef __bf16 bf16x4 __attribute__((ext_vector_type(4)));

__device__ __forceinline__ void load_to_lds16(const void* g, void* l) {
  auto gp = (const __attribute__((address_space(1))) void*)(reinterpret_cast<uintptr_t>(g));
  auto lp = (__attribute__((address_space(3))) void*)(reinterpret_cast<uintptr_t>(l));
  __builtin_amdgcn_global_load_lds(gp, lp, 16, 0, 0);
}

// ---- prep: fp32 -> bf16 + row norms ---------------------------------------
__global__ __launch_bounds__(256) void prep_kernel(const float* __restrict__ f,
                                                   __bf16* __restrict__ fbf,
                                                   float* __restrict__ sq) {
  const int t = threadIdx.x;
  const int row = blockIdx.x * 2 + (t >> 7);
  const int ci = (t & 127) * 4;
  const float4 v = *(const float4*)(f + (size_t)row * DIM + ci);
  bf16x4 b;
  b[0] = (__bf16)v.x; b[1] = (__bf16)v.y; b[2] = (__bf16)v.z; b[3] = (__bf16)v.w;
  *(bf16x4*)(fbf + (size_t)row * DIM + ci) = b;
  float s = v.x * v.x + v.y * v.y + v.z * v.z + v.w * v.w;
#pragma unroll
  for (int off = 1; off < 64; off <<= 1) s += __shfl_xor(s, off, 64);
  __shared__ float red[4];
  if ((t & 63) == 0) red[t >> 6] = s;
  __syncthreads();
  if ((t & 127) == 0) sq[row] = red[t >> 6] + red[(t >> 6) + 1];
}

// ---- fused GEMM (upper tri, banded XCD order, BK=64) + partial epilogue ---
__global__ __launch_bounds__(256) void gemm_kernel(const __bf16* __restrict__ fbf,
                                                   const float* __restrict__ sq,
                                                   float* __restrict__ rowpart,
                                                   float* __restrict__ colpart,
                                                   float* __restrict__ spart) {
  // two XOR-swizzled 8KB sub-regions (ks=0/1) per tensor
  __shared__ __bf16 aT[128 * 64];
  __shared__ __bf16 bT[128 * 64];

  // R5's banded tile decode (empirically best): XCD x owns row-bands
  // by in [4x,4x+4) and [60-4x,64-4x), bx-major, 260 tiles each.
  int by, bx;
  {
    const int x = blockIdx.x & 7;
    int kk = blockIdx.x >> 3;
    int band = x;
    const int n1 = 250 - 16 * x;
    if (kk >= n1) { kk -= n1; band = 15 - x; }
    const int by0 = band * 4;
    int bxx = by0;
    int cnt;
    while (kk >= (cnt = min(4, bxx - by0 + 1))) { kk -= cnt; ++bxx; }
    by = by0 + kk;
    bx = bxx;
  }
  const int brow = by * 128;
  const int bcol = bx * 128;
  // dense upper-tri index for the partial buffers
  const int tn = by * 64 - (by * (by - 1)) / 2 + (bx - by);

  const int t = threadIdx.x;
  const int lane = t & 63;
  const int w = t >> 6;
  const int wrow = (w >> 1) * 64;
  const int wcol = (w & 1) * 64;
  const int q4 = lane >> 4;  // 0..3
  const int lc = lane & 15;  // 0..15

  floatx4 acc[4][4] = {};

  // staging lane -> (global row, 16B chunk) under XOR swizzle (per sub-region):
  // LDS slot (rp, u') holds global (row = rp*2 + (u>>2), chunk = u&3), u = u'^(rp&7)
  int grow[2], gofs[2];
#pragma unroll
  for (int it = 0; it < 2; ++it) {
    const int slot = it * 256 + t;
    const int rp = slot >> 3;
    const int u = (slot & 7) ^ (rp & 7);
    grow[it] = rp * 2 + (u >> 2);
    gofs[it] = (u & 3) * 8;
  }

  // fragment-read swizzle: u = (rr&1)*4+q4, u' = u ^ ((rr>>1)&7); rr = lc here.
  const int up = (((lc & 1) * 4) + q4) ^ (lc >> 1);
  const int rhalf = lc >> 1;

  for (int kt = 0; kt < DIM / 64; ++kt) {
    const int k0 = kt * 64;
#pragma unroll
    for (int it = 0; it < 2; ++it) {
#pragma unroll
      for (int ks = 0; ks < 2; ++ks) {
        load_to_lds16(fbf + (size_t)(brow + grow[it]) * DIM + k0 + ks * 32 + gofs[it],
                      &aT[ks * 4096 + it * 2048 + t * 8]);
        load_to_lds16(fbf + (size_t)(bcol + grow[it]) * DIM + k0 + ks * 32 + gofs[it],
                      &bT[ks * 4096 + it * 2048 + t * 8]);
      }
    }
    __syncthreads();
#pragma unroll
    for (int ks = 0; ks < 2; ++ks) {
      bf16x8 af[4], bfr[4];
#pragma unroll
      for (int mr = 0; mr < 4; ++mr)
        af[mr] = *(const bf16x8*)&aT[ks * 4096 + ((wrow >> 1) + mr * 8 + rhalf) * 64 + up * 8];
#pragma unroll
      for (int mc = 0; mc < 4; ++mc)
        bfr[mc] = *(const bf16x8*)&bT[ks * 4096 + ((wcol >> 1) + mc * 8 + rhalf) * 64 + up * 8];
#pragma unroll
      for (int mr = 0; mr < 4; ++mr)
#pragma unroll
        for (int mc = 0; mc < 4; ++mc)
          acc[mr][mc] =
              __builtin_amdgcn_mfma_f32_16x16x32_bf16(af[mr], bfr[mc], acc[mr][mc], 0, 0, 0);
    }
    __syncthreads();
  }

  // Epilogue. C/D layout: col = lane&15, row = (lane>>4)*4 + reg.
  // LDS reuse after last barrier: redf[256] (row halves), colf[256] (col halves).
  float* redf = (float*)aT;
  float* colf = ((float*)aT) + 256;

  float sqc[4];
#pragma unroll
  for (int mc = 0; mc < 4; ++mc) sqc[mc] = sq[bcol + wcol + mc * 16 + lc];

  float cs[4] = {0.f, 0.f, 0.f, 0.f};  // column partial sums

#pragma unroll
  for (int mr = 0; mr < 4; ++mr) {
#pragma unroll
    for (int reg = 0; reg < 4; ++reg) {
      const int rl = wrow + mr * 16 + q4 * 4 + reg;  // row local 0..127
      const int r = brow + rl;
      const float sr = sq[r];
      const int pc = r ^ (N2 / 2);
      float rs = 0.f;
#pragma unroll
      for (int mc = 0; mc < 4; ++mc) {
        const int c = bcol + wcol + mc * 16 + lc;
        const float g = acc[mr][mc][reg];
        const float d2 = fmaxf(sr + sqc[mc] - 2.f * g, 0.f);
        const float s = T2 * __builtin_amdgcn_rcpf(d2 + T2);
        if (c != r) rs += s;  // diagonal excluded exactly (diag tiles only)
        cs[mc] += s;          // colpart never read for diag tiles
        if (c == pc) { spart[r] = s; spart[pc] = s; }  // off-diag only, 1 lane
      }
#pragma unroll
      for (int off = 1; off < 16; off <<= 1) rs += __shfl_xor(rs, off, 64);
      // waves w&1==0/1 cover disjoint LDS halves; no ordering needed
      if (lc == 0) redf[(w & 1) * 128 + rl] = rs;
    }
  }

  // column sums: reduce over the 4 q4 row-groups within the wave
#pragma unroll
  for (int mc = 0; mc < 4; ++mc) {
    float v = cs[mc];
    v += __shfl_xor(v, 16, 64);
    v += __shfl_xor(v, 32, 64);
    if (lane < 16) colf[(w >> 1) * 128 + wcol + mc * 16 + lane] = v;
  }

  __syncthreads();
  if (t < 128) rowpart[(size_t)tn * 128 + t] = redf[t] + redf[t + 128];
  else         colpart[(size_t)tn * 128 + (t - 128)] = colf[t - 128] + colf[t];
}

// ---- reduce: sum per-tile partials into rowsum (plain stores) -------------
__global__ __launch_bounds__(256) void reduce_kernel(const float* __restrict__ rowpart,
                                                     const float* __restrict__ colpart,
                                                     float* __restrict__ rowsum) {
  const int r = blockIdx.x * 256 + threadIdx.x;
  const int b = r >> 7;
  const int rl = r & 127;
  float s = 0.f;
  // row terms: tiles (b, bx), bx=b..63 -> consecutive tn starting at base
  const int base = b * 64 - (b * (b - 1)) / 2;
  for (int i = 0; i < 64 - b; ++i) s += rowpart[(size_t)(base + i) * 128 + rl];
  // col terms: tiles (by, b), by=0..b-1 (strictly off-diag)
  for (int byi = 0; byi < b; ++byi) {
    const int tn = byi * 64 - (byi * (byi - 1)) / 2 + (b - byi);
    s += colpart[(size_t)tn * 128 + rl];
  }
  rowsum[r] = s;
}

// ---- final scalar reduction ---------------------------------------------
__global__ __launch_bounds__(256) void final_kernel(const float* __restrict__ rowsum,
                                                    const float* __restrict__ spart,
                                                    float* __restrict__ out) {
  const int t = threadIdx.x;
  float a = 0.f;
  for (int r = t; r < N2; r += 256) a += logf(rowsum[r]) - logf(spart[r]);
#pragma unroll
  for (int off = 1; off < 64; off <<= 1) a += __shfl_xor(a, off, 64);
  __shared__ float red[4];
  if ((t & 63) == 0) red[t >> 6] = a;
  __syncthreads();
  if (t == 0) out[0] = (red[0] + red[1] + red[2] + red[3]) * (1.0f / (float)N2);
}

extern "C" void kernel_launch(void* const* d_in, const int* in_sizes, int n_in,
                              void* d_out, int out_size, void* d_ws, size_t ws_size,
                              hipStream_t stream) {
  const float* features = (const float*)d_in[0];
  float* out = (float*)d_out;

  char* ws = (char*)d_ws;
  __bf16* fbf = (__bf16*)ws;                                     // 8 MB
  float* sq = (float*)(ws + (size_t)N2 * DIM * sizeof(__bf16));  // 32 KB
  float* rowsum = sq + N2;                                       // 32 KB
  float* spart = rowsum + N2;                                    // 32 KB
  float* rowpart = spart + N2;                                   // 2080*128*4 = 1.04 MB
  float* colpart = rowpart + (size_t)NTILES * 128;               // 1.04 MB

  prep_kernel<<<N2 / 2, 256, 0, stream>>>(features, fbf, sq);
  gemm_kernel<<<NTILES, 256, 0, stream>>>(fbf, sq, rowpart, colpart, spart);
  reduce_kernel<<<N2 / 256, 256, 0, stream>>>(rowpart, colpart, rowsum);
  final_kernel<<<1, 256, 0, stream>>>(rowsum, spart, out);
}

// Round 9
// 170.533 us; speedup vs baseline: 1.3631x; 1.0121x over previous
//
#include <hip/hip_runtime.h>

// InfoCNECauchy: loss = mean_r log(sum_{j!=r} sim[r,j]) - mean_r log(sim[r, r^4096])
// sim = t^2/(d2+t^2), d2 = ||f_r||^2 + ||f_c||^2 - 2<f_r,f_c>, t=0.07
//
// R12 (resubmit #2; R8 bench was a GPUAcquisitionTimeout, experiment never
// ran): R8 verbatim (BK=64, banded XCD map, XOR-swizzled LDS, 0 conflicts,
// gemm 70.6us = best) with ONE change: final_kernel FUSED into gemm as a
// last-block tail. Rationale: accounting across 7 rounds shows
// total - sum(kernel dur) ~ 65-74us for 3-kernel variants and ~90us for the
// 4-kernel one => per-launch overhead ~15-20us dominates everything we've
// been micro-tuning (six falsified gemm theories). Atomics were exonerated
// by R11 (removing them: WRITE 10.4->2.1MB but SLOWER).
// Tail correctness WITHOUT L2-flush fences (R3/R4 poison): all cross-block
// data moves through coherence-point ops only -- rowsum via atomicAdd (RMWs
// never allocate in the non-coherent per-XCD L2s), spart via agent-scope
// atomic stores (bypass L2, ~8192 total), counter via device atomicAdd after
// vmcnt(0)+barrier (all this block's atomics performed first). Last block's
// plain loads of rowsum/spart miss its L2 (no lines ever allocated) -> L3 ->
// fresh. No spin, no cooperative launch, no buffer_wbl2.

#define N2 8192
#define DIM 512
#define NT 64 /* 8192/128 tiles per dim */
#define NTILES (NT * (NT + 1) / 2)
#define T2 0.0049f

typedef float floatx4 __attribute__((ext_vector_type(4)));
typedef __bf16 bf16x8 __attribute__((ext_vector_type(8)));
typedef __bf16 bf16x4 __attribute__((ext_vector_type(4)));

__device__ __forceinline__ void load_to_lds16(const void* g, void* l) {
  auto gp = (const __attribute__((address_space(1))) void*)(reinterpret_cast<uintptr_t>(g));
  auto lp = (__attribute__((address_space(3))) void*)(reinterpret_cast<uintptr_t>(l));
  __builtin_amdgcn_global_load_lds(gp, lp, 16, 0, 0);
}

// ---- prep: fp32 -> bf16 + row norms + zero rowsum & counter ---------------
__global__ __launch_bounds__(256) void prep_kernel(const float* __restrict__ f,
                                                   __bf16* __restrict__ fbf,
                                                   float* __restrict__ sq,
                                                   float* __restrict__ rowsum,
                                                   int* __restrict__ counter) {
  const int t = threadIdx.x;
  if (t < 2) rowsum[blockIdx.x * 2 + t] = 0.f;
  if (blockIdx.x == 0 && t == 0) *counter = 0;
  const int row = blockIdx.x * 2 + (t >> 7);
  const int ci = (t & 127) * 4;
  const float4 v = *(const float4*)(f + (size_t)row * DIM + ci);
  bf16x4 b;
  b[0] = (__bf16)v.x; b[1] = (__bf16)v.y; b[2] = (__bf16)v.z; b[3] = (__bf16)v.w;
  *(bf16x4*)(fbf + (size_t)row * DIM + ci) = b;
  float s = v.x * v.x + v.y * v.y + v.z * v.z + v.w * v.w;
#pragma unroll
  for (int off = 1; off < 64; off <<= 1) s += __shfl_xor(s, off, 64);
  __shared__ float red[4];
  if ((t & 63) == 0) red[t >> 6] = s;
  __syncthreads();
  if ((t & 127) == 0) sq[row] = red[t >> 6] + red[(t >> 6) + 1];
}

// ---- fused GEMM (upper tri, banded XCD order, BK=64) + epilogue + tail ----
__global__ __launch_bounds__(256) void gemm_kernel(const __bf16* __restrict__ fbf,
                                                   const float* __restrict__ sq,
                                                   float* __restrict__ rowsum,
                                                   float* __restrict__ spart,
                                                   int* __restrict__ counter,
                                                   float* __restrict__ out) {
  // two XOR-swizzled 8KB sub-regions (ks=0/1) per tensor
  __shared__ __bf16 aT[128 * 64];
  __shared__ __bf16 bT[128 * 64];

  // R5's banded tile decode (empirically best): XCD x owns row-bands
  // by in [4x,4x+4) and [60-4x,64-4x), bx-major, 260 tiles each.
  int by, bx;
  {
    const int x = blockIdx.x & 7;
    int kk = blockIdx.x >> 3;
    int band = x;
    const int n1 = 250 - 16 * x;
    if (kk >= n1) { kk -= n1; band = 15 - x; }
    const int by0 = band * 4;
    int bxx = by0;
    int cnt;
    while (kk >= (cnt = min(4, bxx - by0 + 1))) { kk -= cnt; ++bxx; }
    by = by0 + kk;
    bx = bxx;
  }
  const int brow = by * 128;
  const int bcol = bx * 128;
  const bool diag = (by == bx);

  const int t = threadIdx.x;
  const int lane = t & 63;
  const int w = t >> 6;
  const int wrow = (w >> 1) * 64;
  const int wcol = (w & 1) * 64;
  const int q4 = lane >> 4;  // 0..3
  const int lc = lane & 15;  // 0..15

  floatx4 acc[4][4] = {};

  // staging lane -> (global row, 16B chunk) under XOR swizzle (per sub-region):
  // LDS slot (rp, u') holds global (row = rp*2 + (u>>2), chunk = u&3), u = u'^(rp&7)
  int grow[2], gofs[2];
#pragma unroll
  for (int it = 0; it < 2; ++it) {
    const int slot = it * 256 + t;
    const int rp = slot >> 3;
    const int u = (slot & 7) ^ (rp & 7);
    grow[it] = rp * 2 + (u >> 2);
    gofs[it] = (u & 3) * 8;
  }

  // fragment-read swizzle: u = (rr&1)*4+q4, u' = u ^ ((rr>>1)&7); rr = lc here.
  const int up = (((lc & 1) * 4) + q4) ^ (lc >> 1);
  const int rhalf = lc >> 1;

  for (int kt = 0; kt < DIM / 64; ++kt) {
    const int k0 = kt * 64;
#pragma unroll
    for (int it = 0; it < 2; ++it) {
#pragma unroll
      for (int ks = 0; ks < 2; ++ks) {
        load_to_lds16(fbf + (size_t)(brow + grow[it]) * DIM + k0 + ks * 32 + gofs[it],
                      &aT[ks * 4096 + it * 2048 + t * 8]);
        load_to_lds16(fbf + (size_t)(bcol + grow[it]) * DIM + k0 + ks * 32 + gofs[it],
                      &bT[ks * 4096 + it * 2048 + t * 8]);
      }
    }
    __syncthreads();
#pragma unroll
    for (int ks = 0; ks < 2; ++ks) {
      bf16x8 af[4], bfr[4];
#pragma unroll
      for (int mr = 0; mr < 4; ++mr)
        af[mr] = *(const bf16x8*)&aT[ks * 4096 + ((wrow >> 1) + mr * 8 + rhalf) * 64 + up * 8];
#pragma unroll
      for (int mc = 0; mc < 4; ++mc)
        bfr[mc] = *(const bf16x8*)&bT[ks * 4096 + ((wcol >> 1) + mc * 8 + rhalf) * 64 + up * 8];
#pragma unroll
      for (int mr = 0; mr < 4; ++mr)
#pragma unroll
        for (int mc = 0; mc < 4; ++mc)
          acc[mr][mc] =
              __builtin_amdgcn_mfma_f32_16x16x32_bf16(af[mr], bfr[mc], acc[mr][mc], 0, 0, 0);
    }
    __syncthreads();
  }

  // Epilogue. C/D layout: col = lane&15, row = (lane>>4)*4 + reg.
  float sqc[4];
#pragma unroll
  for (int mc = 0; mc < 4; ++mc) sqc[mc] = sq[bcol + wcol + mc * 16 + lc];

  float cs[4] = {0.f, 0.f, 0.f, 0.f};  // column partial sums (off-diag tiles)

#pragma unroll
  for (int mr = 0; mr < 4; ++mr) {
#pragma unroll
    for (int reg = 0; reg < 4; ++reg) {
      const int r = brow + wrow + mr * 16 + q4 * 4 + reg;
      const float sr = sq[r];
      const int pc = r ^ (N2 / 2);
      float rs = 0.f;
#pragma unroll
      for (int mc = 0; mc < 4; ++mc) {
        const int c = bcol + wcol + mc * 16 + lc;
        const float g = acc[mr][mc][reg];
        const float d2 = fmaxf(sr + sqc[mc] - 2.f * g, 0.f);
        const float s = T2 * __builtin_amdgcn_rcpf(d2 + T2);
        if (c != r) rs += s;  // diagonal excluded exactly (diag tiles only)
        cs[mc] += s;          // unused on diag tiles
        if (c == pc) {        // off-diag only, 1 lane; agent-scope store (bypass L2)
          __hip_atomic_store(&spart[r], s, __ATOMIC_RELAXED, __HIP_MEMORY_SCOPE_AGENT);
          __hip_atomic_store(&spart[pc], s, __ATOMIC_RELAXED, __HIP_MEMORY_SCOPE_AGENT);
        }
      }
#pragma unroll
      for (int off = 1; off < 16; off <<= 1) rs += __shfl_xor(rs, off, 64);
      if (lc == 0) atomicAdd(&rowsum[r], rs);
    }
  }

  if (!diag) {
#pragma unroll
    for (int mc = 0; mc < 4; ++mc) {
      float v = cs[mc];
      v += __shfl_xor(v, 16, 64);
      v += __shfl_xor(v, 32, 64);
      if (lane < 16) atomicAdd(&rowsum[bcol + wcol + mc * 16 + lane], v);
    }
  }

  // ---- last-block tail: fused final reduction (saves one kernel launch) ---
  // All this block's rowsum/spart ops are VMEM; drain them to the coherence
  // point before signaling (vmcnt(0)), then barrier so ALL waves have drained.
  asm volatile("s_waitcnt vmcnt(0)" ::: "memory");
  __shared__ int lastFlag;
  __syncthreads();
  if (t == 0) {
    const int prev =
        __hip_atomic_fetch_add(counter, 1, __ATOMIC_RELAXED, __HIP_MEMORY_SCOPE_AGENT);
    lastFlag = (prev == NTILES - 1);
  }
  __syncthreads();
  if (lastFlag) {
    // Everyone else's rowsum atomics & spart agent-stores are at the
    // coherence point (they drained before their counter add). This block's
    // L2 holds no rowsum/spart lines (only RMW/bypass ops touched them), so
    // plain loads fetch fresh data from L3.
    float a = 0.f;
    for (int r = t; r < N2; r += 256) a += logf(rowsum[r]) - logf(spart[r]);
#pragma unroll
    for (int off = 1; off < 64; off <<= 1) a += __shfl_xor(a, off, 64);
    __shared__ float red[4];
    if ((t & 63) == 0) red[t >> 6] = a;
    __syncthreads();
    if (t == 0) out[0] = (red[0] + red[1] + red[2] + red[3]) * (1.0f / (float)N2);
  }
}

extern "C" void kernel_launch(void* const* d_in, const int* in_sizes, int n_in,
                              void* d_out, int out_size, void* d_ws, size_t ws_size,
                              hipStream_t stream) {
  const float* features = (const float*)d_in[0];
  float* out = (float*)d_out;

  char* ws = (char*)d_ws;
  __bf16* fbf = (__bf16*)ws;                                     // 8 MB
  float* sq = (float*)(ws + (size_t)N2 * DIM * sizeof(__bf16));  // 32 KB
  float* rowsum = sq + N2;                                       // 32 KB
  float* spart = rowsum + N2;                                    // 32 KB
  int* counter = (int*)(spart + N2);                             // 4 B

  prep_kernel<<<N2 / 2, 256, 0, stream>>>(features, fbf, sq, rowsum, counter);
  gemm_kernel<<<NTILES, 256, 0, stream>>>(fbf, sq, rowsum, spart, counter, out);
}